// Round 7
// baseline (610.464 us; speedup 1.0000x reference)
//
#include <hip/hip_runtime.h>

// GRU cell, B=32768, I=H=512, fp32 in/out, bf16 MFMA internals.
// R10: zero-LDS line abandoned (unmeasurable under infra failures; R9 bisect
// inconclusive). Revert to the proven R5 skeleton (gload_lds staging, counted
// vmcnt, two barriers per K-step) and attack the LDS-pipe bound seen in R5's
// counters (MfmaUtil 21%, 1285 cy/step vs 80 cy MFMA): tile grows 128x128 ->
// 256x128 with 8 waves (4x2), cutting LDS bytes/FLOP 1.57x while keeping
// stage=24KB, NBUF=3 (72KB) -> 2 blocks/CU overlap preserved. Depth-2
// prefetch (race-free under two-barrier structure), vmcnt 6/3/0.
// Numerics identical to R5.
//
// ws layout (bytes):
//   [0,          2097152)   Wzr_t : bf16 B-tiles pass1, 32kt x 8nt x (128x32)
//   [2097152,    3145728)   Whh_t : bf16 B-tiles pass2, 32kt x 4nt x (128x32)
//   [3145728,   70254592)   XHt   : bf16 A-tiles [x|h], 256mt x 32kt x (128x32)
//   [70254592, 103809024)   HRt   : bf16 A-tiles h*r,   256mt x 16kt x (128x32)
//   [103809024,137363456)   Z     : z gate bf16 [32768][512]

#define BATCH 32768
#define HD 512
#define TS 4096                    // tile shorts: 128 rows x 32 k (8192 B)
#define STG_SHORTS 12288           // [B 8KB | A0 8KB | A1 8KB] = 24576 B
#define NBUF 3

typedef __attribute__((ext_vector_type(8))) short short8v;
typedef __attribute__((ext_vector_type(4))) float float4v;

typedef __attribute__((address_space(1))) unsigned int gu32_t;
typedef __attribute__((address_space(3))) unsigned int lu32_t;

__device__ __forceinline__ unsigned short f2bf(float f) {
  unsigned u = __float_as_uint(f);
  u += 0x7fffu + ((u >> 16) & 1u);   // round-to-nearest-even
  return (unsigned short)(u >> 16);
}
__device__ __forceinline__ float bf2f(unsigned short s) {
  return __uint_as_float(((unsigned)s) << 16);
}

// async 16B/lane global->LDS DMA. g is per-lane address, l is wave-uniform.
__device__ __forceinline__ void async_cp16(const void* g, void* l) {
  __builtin_amdgcn_global_load_lds(
      (gu32_t*)(unsigned long long)g,
      (lu32_t*)(unsigned int)(unsigned long long)l,
      16, 0, 0);
}

__device__ __forceinline__ float fast_sigmoid(float v) {
  return 1.0f / (1.0f + __expf(-v));
}
__device__ __forceinline__ float fast_tanh(float v) {
  float e = __expf(2.0f * v);
  return 1.0f - 2.0f / (e + 1.0f);
}

// swizzled short-index of element (r, c) within a 128x32 tile.
// XOR of bits 3..5 with row&7. Bijective; writers and readers agree.
__device__ __forceinline__ int swz_idx(int r, int c) {
  return ((r << 5) + c) ^ ((r & 7) << 3);
}

// ---------------------------------------------------------------------------
// prep_all (R5 verbatim): blocks [0,8192) convert x,h -> XHt bf16 A-tiles;
//                         blocks [8192,14336) scatter weights -> bf16 B-tiles.
// ---------------------------------------------------------------------------
__global__ __launch_bounds__(256) void prep_all(
    const float* __restrict__ x, const float* __restrict__ h,
    const float* __restrict__ Wz, const float* __restrict__ Wr,
    const float* __restrict__ Uz, const float* __restrict__ Ur,
    const float* __restrict__ Wh, const float* __restrict__ Uh,
    unsigned short* __restrict__ XHt,
    unsigned short* __restrict__ Wzr_t, unsigned short* __restrict__ Whh_t) {
  int b = blockIdx.x;
  int t = threadIdx.x;
  if (b < 8192) {
    int kt = b & 31, mt = b >> 5;
    const float* src = (kt < 16)
        ? (x + (size_t)(mt * 128) * HD + kt * 32)
        : (h + (size_t)(mt * 128) * HD + (kt - 16) * 32);
    unsigned short* dst = XHt + (size_t)b * TS;
    int r0 = t >> 3, c0 = (t & 7) * 4;
#pragma unroll
    for (int it = 0; it < 4; ++it) {
      int r = r0 + it * 32;
      float4 v = *(const float4*)(src + (size_t)r * HD + c0);
      short4 s;
      s.x = (short)f2bf(v.x); s.y = (short)f2bf(v.y);
      s.z = (short)f2bf(v.z); s.w = (short)f2bf(v.w);
      *(short4*)(dst + swz_idx(r, c0)) = s;
    }
  } else {
    int e = (b - 8192) * 256 + t;
    if (e < 256 * TS) {
      int tile = e >> 12, rem = e & 4095;
      int r = rem >> 5, c = rem & 31;
      int kt = tile >> 3, nt = tile & 7;
      int n = nt * 128 + r;       // 0..1023
      int k = kt * 32 + c;        // 0..1023
      int nn = (n < 512) ? n : (n - 512);
      float v;
      if (k < 512) v = (n < 512) ? Wz[nn * 512 + k] : Wr[nn * 512 + k];
      else         v = (n < 512) ? Uz[nn * 512 + (k - 512)] : Ur[nn * 512 + (k - 512)];
      Wzr_t[(tile << 12) + (rem ^ ((r & 7) << 3))] = f2bf(v);
    } else {
      int e2 = e - 256 * TS;
      if (e2 < 128 * TS) {
        int tile = e2 >> 12, rem = e2 & 4095;
        int r = rem >> 5, c = rem & 31;
        int kt = tile >> 2, nt = tile & 3;
        int n = nt * 128 + r;     // 0..511
        int k = kt * 32 + c;      // 0..1023
        float v = (k < 512) ? Wh[n * 512 + k] : Uh[n * 512 + (k - 512)];
        Whh_t[(tile << 12) + (rem ^ ((r & 7) << 3))] = f2bf(v);
      }
    }
  }
}

// ---------------------------------------------------------------------------
// staging: 24 x 1KB chunks, wave w issues chunks 3w..3w+2 (uniform: 3/wave).
// stage = [B tile | A tile rows 0-127 | A tile rows 128-255]
// ---------------------------------------------------------------------------
__device__ __forceinline__ void prefetch3(const unsigned short* __restrict__ Bt,
                                          const unsigned short* __restrict__ A0,
                                          const unsigned short* __restrict__ A1,
                                          unsigned short* stage,
                                          int wave, int lane) {
#pragma unroll
  for (int i = 0; i < 3; ++i) {
    int c = wave * 3 + i;                       // 0..23, wave-uniform
    const unsigned short* src = (c < 8)  ? (Bt + c * 512)
                              : (c < 16) ? (A0 + (c - 8) * 512)
                                         : (A1 + (c - 16) * 512);
    async_cp16((const char*)src + lane * 16, (char*)stage + c * 1024);
  }
}

// per-wave 64x64 output quadrant of the 256x128 block tile.
__device__ __forceinline__ void mfma_step(const unsigned short* stage,
                                          float4v acc[4][4],
                                          int wm, int wn, int quad, int l16) {
  const int sw = (l16 & 7) << 3;   // row&7 == l16&7 (wm, i*16 multiples of 16)
  short8v a[4], b[4];
#pragma unroll
  for (int i = 0; i < 4; ++i) {
    int r = wm + i * 16 + l16;     // 0..255
    const unsigned short* base = stage + 4096 + ((r >> 7) << 12);
    a[i] = *(const short8v*)(base + ((((r & 127) << 5) + (quad << 3)) ^ sw));
  }
#pragma unroll
  for (int j = 0; j < 4; ++j) {
    int r = wn + j * 16 + l16;     // 0..127
    b[j] = *(const short8v*)(stage + (((r << 5) + (quad << 3)) ^ sw));
  }
#pragma unroll
  for (int i = 0; i < 4; ++i)
#pragma unroll
    for (int j = 0; j < 4; ++j)
      acc[i][j] = __builtin_amdgcn_mfma_f32_16x16x32_bf16(a[i], b[j], acc[i][j], 0, 0, 0);
}

// depth-2 pipeline, 3 loads/wave/stage: after issuing batch kt+2, in-flight =
// {kt+1, kt+2} = 6 -> vmcnt(6) retires batch kt. Tail 3/0.
#define WAIT_VM6()  asm volatile("s_waitcnt vmcnt(6)" ::: "memory")
#define WAIT_VM3()  asm volatile("s_waitcnt vmcnt(3)" ::: "memory")
#define WAIT_VM0()  asm volatile("s_waitcnt vmcnt(0)" ::: "memory")
#define RAW_BAR()   asm volatile("s_barrier" ::: "memory")

// ---------------------------------------------------------------------------
// pass 1: pre_zr = [x|h] @ B1 ; z = sigmoid -> Z ; r -> HRt = bf16(h*r)
// 256x128 tile, 8 waves (wm 4-way x wn 2-way). grid 1024:
// xcd=b&7, q=b>>3, nt=q&7, bm=(b&7)*16+(q>>3)
// ---------------------------------------------------------------------------
__global__ __launch_bounds__(512, 4) void gemm_zr(
    const float* __restrict__ h,
    const unsigned short* __restrict__ XHt,
    const unsigned short* __restrict__ Wt,
    const float* __restrict__ Wz_b, const float* __restrict__ Uz_b,
    const float* __restrict__ Wr_b, const float* __restrict__ Ur_b,
    unsigned short* __restrict__ Z, unsigned short* __restrict__ HRt) {
  __shared__ __align__(16) unsigned short Stg[NBUF][STG_SHORTS];  // 72 KB
  const int tid = threadIdx.x;
  const int wave = tid >> 6, lane = tid & 63;
  const int quad = lane >> 4, l16 = lane & 15;
  const int b = blockIdx.x;
  const int q = b >> 3;
  const int nt = q & 7;                    // 0..7
  const int bm = (b & 7) * 16 + (q >> 3);  // 0..127
  const int m0 = bm * 256;
  const int wm = (wave >> 1) * 64;         // 0,64,128,192
  const int wn = (wave & 1) * 64;          // 0,64

  float4v acc[4][4] = {};

  const unsigned short* A0 = XHt + (size_t)(2 * bm) * 32 * TS;
  const unsigned short* A1 = XHt + (size_t)(2 * bm + 1) * 32 * TS;

  prefetch3(Wt + (size_t)nt * TS, A0, A1, Stg[0], wave, lane);
  prefetch3(Wt + (size_t)(8 + nt) * TS, A0 + TS, A1 + TS, Stg[1], wave, lane);
  for (int kt = 0; kt < 32; ++kt) {
    if (kt <= 29) {
      int kn = kt + 2;
      prefetch3(Wt + (size_t)(kn * 8 + nt) * TS,
                A0 + (size_t)kn * TS, A1 + (size_t)kn * TS,
                Stg[kn % NBUF], wave, lane);
      WAIT_VM6();
    } else if (kt == 30) {
      WAIT_VM3();
    } else {
      WAIT_VM0();
    }
    RAW_BAR();
    mfma_step(Stg[kt % NBUF], acc, wm, wn, quad, l16);
    RAW_BAR();
  }

  const int n0 = nt * 128;
  if (n0 < 512) {
    // z gate
#pragma unroll
    for (int j = 0; j < 4; ++j) {
      int n = n0 + wn + j * 16 + l16;
      float bias = Wz_b[n] + Uz_b[n];
#pragma unroll
      for (int i = 0; i < 4; ++i) {
#pragma unroll
        for (int reg = 0; reg < 4; ++reg) {
          int m = m0 + wm + i * 16 + quad * 4 + reg;
          float v = fast_sigmoid(acc[i][j][reg] + bias);
          Z[(size_t)m * HD + n] = f2bf(v);
        }
      }
    }
  } else {
    // r gate -> hr = h*r, stored pre-tiled (swizzled) as pass-2 A tiles
#pragma unroll
    for (int j = 0; j < 4; ++j) {
      int nn = (n0 - 512) + wn + j * 16 + l16;   // 0..511
      float bias = Wr_b[nn] + Ur_b[nn];
      int ktile = nn >> 5, kc = nn & 31;
#pragma unroll
      for (int i = 0; i < 4; ++i) {
#pragma unroll
        for (int reg = 0; reg < 4; ++reg) {
          int m = m0 + wm + i * 16 + quad * 4 + reg;
          float rv = fast_sigmoid(acc[i][j][reg] + bias);
          float hv = h[(size_t)m * HD + nn];
          int mt = m >> 7, mr = m & 127;
          HRt[(size_t)(mt * 16 + ktile) * TS + swz_idx(mr, kc)] = f2bf(hv * rv);
        }
      }
    }
  }
}

// ---------------------------------------------------------------------------
// pass 2: pre_h = [x|hr] @ B2 ; ht = tanh ; h_next = h + z*(ht - h) -> out x2
// 256x128 tile, 8 waves. grid 512: xcd=b&7, q=b>>3, nt=q&3, bm=(b&7)*16+(q>>2)
// ---------------------------------------------------------------------------
__global__ __launch_bounds__(512, 4) void gemm_out(
    const float* __restrict__ h,
    const unsigned short* __restrict__ XHt,
    const unsigned short* __restrict__ Wt,
    const float* __restrict__ Wh_b, const float* __restrict__ Uh_b,
    const unsigned short* __restrict__ Z, const unsigned short* __restrict__ HRt,
    float* __restrict__ out) {
  __shared__ __align__(16) unsigned short Stg[NBUF][STG_SHORTS];  // 72 KB
  const int tid = threadIdx.x;
  const int wave = tid >> 6, lane = tid & 63;
  const int quad = lane >> 4, l16 = lane & 15;
  const int b = blockIdx.x;
  const int q = b >> 3;
  const int nt = q & 3;                    // 0..3
  const int bm = (b & 7) * 16 + (q >> 2);  // 0..127
  const int m0 = bm * 256;
  const int wm = (wave >> 1) * 64;
  const int wn = (wave & 1) * 64;

  float4v acc[4][4] = {};

  const unsigned short* A0x = XHt + (size_t)(2 * bm) * 32 * TS;
  const unsigned short* A1x = XHt + (size_t)(2 * bm + 1) * 32 * TS;
  const unsigned short* A0h = HRt + (size_t)(2 * bm) * 16 * TS;
  const unsigned short* A1h = HRt + (size_t)(2 * bm + 1) * 16 * TS;
#define AT0(kn) ((kn) < 16 ? (A0x + (size_t)(kn) * TS) : (A0h + (size_t)((kn) - 16) * TS))
#define AT1(kn) ((kn) < 16 ? (A1x + (size_t)(kn) * TS) : (A1h + (size_t)((kn) - 16) * TS))

  prefetch3(Wt + (size_t)nt * TS, AT0(0), AT1(0), Stg[0], wave, lane);
  prefetch3(Wt + (size_t)(4 + nt) * TS, AT0(1), AT1(1), Stg[1], wave, lane);
  for (int kt = 0; kt < 32; ++kt) {
    if (kt <= 29) {
      int kn = kt + 2;
      prefetch3(Wt + (size_t)(kn * 4 + nt) * TS, AT0(kn), AT1(kn),
                Stg[kn % NBUF], wave, lane);
      WAIT_VM6();
    } else if (kt == 30) {
      WAIT_VM3();
    } else {
      WAIT_VM0();
    }
    RAW_BAR();
    mfma_step(Stg[kt % NBUF], acc, wm, wn, quad, l16);
    RAW_BAR();
  }
#undef AT0
#undef AT1

  const int n0 = nt * 128;
#pragma unroll
  for (int j = 0; j < 4; ++j) {
    int n = n0 + wn + j * 16 + l16;
    float bias = Wh_b[n] + Uh_b[n];
#pragma unroll
    for (int i = 0; i < 4; ++i) {
#pragma unroll
      for (int reg = 0; reg < 4; ++reg) {
        int m = m0 + wm + i * 16 + quad * 4 + reg;
        size_t idx = (size_t)m * HD + n;
        float ht = fast_tanh(acc[i][j][reg] + bias);
        float hv = h[idx];
        float zv = bf2f(Z[idx]);
        float o = fmaf(zv, ht - hv, hv);
        out[idx] = o;
        out[(size_t)BATCH * HD + idx] = o;
      }
    }
  }
}

// ---------------------------------------------------------------------------
extern "C" void kernel_launch(void* const* d_in, const int* in_sizes, int n_in,
                              void* d_out, int out_size, void* d_ws, size_t ws_size,
                              hipStream_t stream) {
  const float* x    = (const float*)d_in[0];
  const float* h    = (const float*)d_in[1];
  const float* Wz_w = (const float*)d_in[2];
  const float* Wz_b = (const float*)d_in[3];
  const float* Wr_w = (const float*)d_in[4];
  const float* Wr_b = (const float*)d_in[5];
  const float* Wh_w = (const float*)d_in[6];
  const float* Wh_b = (const float*)d_in[7];
  const float* Uz_w = (const float*)d_in[8];
  const float* Uz_b = (const float*)d_in[9];
  const float* Ur_w = (const float*)d_in[10];
  const float* Ur_b = (const float*)d_in[11];
  const float* Uh_w = (const float*)d_in[12];
  const float* Uh_b = (const float*)d_in[13];
  float* out = (float*)d_out;

  char* ws = (char*)d_ws;
  unsigned short* Wzr_t = (unsigned short*)(ws);                //  2,097,152 B
  unsigned short* Whh_t = (unsigned short*)(ws + 2097152);      //  1,048,576 B
  unsigned short* XHt   = (unsigned short*)(ws + 3145728);      // 67,108,864 B
  unsigned short* HRt   = (unsigned short*)(ws + 70254592);     // 33,554,432 B
  unsigned short* Z     = (unsigned short*)(ws + 103809024);    // 33,554,432 B

  prep_all<<<14336, 256, 0, stream>>>(x, h, Wz_w, Wr_w, Uz_w, Ur_w, Wh_w, Uh_w,
                                      XHt, Wzr_t, Whh_t);
  gemm_zr<<<1024, 512, 0, stream>>>(h, XHt, Wzr_t, Wz_b, Uz_b, Wr_b, Ur_b, Z, HRt);
  gemm_out<<<512, 512, 0, stream>>>(h, XHt, Whh_t, Wh_b, Uh_b, Z, HRt, out);
}

// Round 8
// 539.087 us; speedup vs baseline: 1.1324x; 1.1324x over previous
//
#include <hip/hip_runtime.h>

// GRU cell, B=32768, I=H=512, fp32 in/out, bf16 MFMA internals.
// R11: R5 skeleton verbatim (two-barrier lockstep K-loop, gload_lds staging,
// counted vmcnt BEFORE the leading barrier) with ONE isolated change:
// NBUF 4->3 (64->48 KB LDS) + prefetch depth 3->2, raising residency from
// 2 to 3 blocks/CU (12 waves/CU). Register audit: 84 VGPR + 64 AGPR = 148
// <= 170 (3 waves/EU) -> no spill (R10's failure mode). Buffer reuse audit:
// iter kt prefetches buf (kt+2)%3 = (kt-1)%3, consumed at kt-1 whose
// trailing barrier has been passed -> race-free. vmcnt 8/4/0.
// Numerics identical to R5.
//
// ws layout (bytes):
//   [0,          2097152)   Wzr_t : bf16 B-tiles pass1, 32kt x 8nt x (128x32)
//   [2097152,    3145728)   Whh_t : bf16 B-tiles pass2, 32kt x 4nt x (128x32)
//   [3145728,   70254592)   XHt   : bf16 A-tiles [x|h], 256mt x 32kt x (128x32)
//   [70254592, 103809024)   HRt   : bf16 A-tiles h*r,   256mt x 16kt x (128x32)
//   [103809024,137363456)   Z     : z gate bf16 [32768][512]

#define BATCH 32768
#define HD 512
#define TS 4096                    // tile shorts: 128 rows x 32 k (8192 B)
#define STAGE_SHORTS (2 * TS)      // [B tile | A tile] = 16384 B
#define NBUF 3

typedef __attribute__((ext_vector_type(8))) short short8v;
typedef __attribute__((ext_vector_type(4))) float float4v;

typedef __attribute__((address_space(1))) unsigned int gu32_t;
typedef __attribute__((address_space(3))) unsigned int lu32_t;

__device__ __forceinline__ unsigned short f2bf(float f) {
  unsigned u = __float_as_uint(f);
  u += 0x7fffu + ((u >> 16) & 1u);   // round-to-nearest-even
  return (unsigned short)(u >> 16);
}
__device__ __forceinline__ float bf2f(unsigned short s) {
  return __uint_as_float(((unsigned)s) << 16);
}

// async 16B/lane global->LDS DMA. g is per-lane address, l is wave-uniform.
__device__ __forceinline__ void async_cp16(const void* g, void* l) {
  __builtin_amdgcn_global_load_lds(
      (gu32_t*)(unsigned long long)g,
      (lu32_t*)(unsigned int)(unsigned long long)l,
      16, 0, 0);
}

__device__ __forceinline__ float fast_sigmoid(float v) {
  return 1.0f / (1.0f + __expf(-v));
}
__device__ __forceinline__ float fast_tanh(float v) {
  float e = __expf(2.0f * v);
  return 1.0f - 2.0f / (e + 1.0f);
}

// swizzled short-index of element (r, c) within a 128x32 tile.
// XOR of bits 3..5 with row&7. Bijective; writers and readers agree.
__device__ __forceinline__ int swz_idx(int r, int c) {
  return ((r << 5) + c) ^ ((r & 7) << 3);
}

// ---------------------------------------------------------------------------
// prep_all (R5 verbatim): blocks [0,8192) convert x,h -> XHt bf16 A-tiles;
//                         blocks [8192,14336) scatter weights -> bf16 B-tiles.
// ---------------------------------------------------------------------------
__global__ __launch_bounds__(256) void prep_all(
    const float* __restrict__ x, const float* __restrict__ h,
    const float* __restrict__ Wz, const float* __restrict__ Wr,
    const float* __restrict__ Uz, const float* __restrict__ Ur,
    const float* __restrict__ Wh, const float* __restrict__ Uh,
    unsigned short* __restrict__ XHt,
    unsigned short* __restrict__ Wzr_t, unsigned short* __restrict__ Whh_t) {
  int b = blockIdx.x;
  int t = threadIdx.x;
  if (b < 8192) {
    // conv: one 128x32 tile per block, coalesced float4 reads.
    int kt = b & 31, mt = b >> 5;
    const float* src = (kt < 16)
        ? (x + (size_t)(mt * 128) * HD + kt * 32)
        : (h + (size_t)(mt * 128) * HD + (kt - 16) * 32);
    unsigned short* dst = XHt + (size_t)b * TS;
    int r0 = t >> 3, c0 = (t & 7) * 4;
#pragma unroll
    for (int it = 0; it < 4; ++it) {
      int r = r0 + it * 32;
      float4 v = *(const float4*)(src + (size_t)r * HD + c0);
      short4 s;
      s.x = (short)f2bf(v.x); s.y = (short)f2bf(v.y);
      s.z = (short)f2bf(v.z); s.w = (short)f2bf(v.w);
      // swizzle flips bits >=3 only: 4-short granule stays intact
      *(short4*)(dst + swz_idx(r, c0)) = s;
    }
  } else {
    int e = (b - 8192) * 256 + t;
    if (e < 256 * TS) {
      // Wzr: 32kt x 8nt tiles; rows n (output col), cols k
      int tile = e >> 12, rem = e & 4095;
      int r = rem >> 5, c = rem & 31;
      int kt = tile >> 3, nt = tile & 7;
      int n = nt * 128 + r;       // 0..1023
      int k = kt * 32 + c;        // 0..1023
      int nn = (n < 512) ? n : (n - 512);
      float v;
      if (k < 512) v = (n < 512) ? Wz[nn * 512 + k] : Wr[nn * 512 + k];
      else         v = (n < 512) ? Uz[nn * 512 + (k - 512)] : Ur[nn * 512 + (k - 512)];
      Wzr_t[(tile << 12) + (rem ^ ((r & 7) << 3))] = f2bf(v);
    } else {
      int e2 = e - 256 * TS;
      if (e2 < 128 * TS) {
        int tile = e2 >> 12, rem = e2 & 4095;
        int r = rem >> 5, c = rem & 31;
        int kt = tile >> 2, nt = tile & 3;
        int n = nt * 128 + r;     // 0..511
        int k = kt * 32 + c;      // 0..1023
        float v = (k < 512) ? Wh[n * 512 + k] : Uh[n * 512 + (k - 512)];
        Whh_t[(tile << 12) + (rem ^ ((r & 7) << 3))] = f2bf(v);
      }
    }
  }
}

// ---------------------------------------------------------------------------
// staging (R5 verbatim): stage = [B tile (8192 B) | A tile (8192 B)], each
// wave issues exactly 4 x 1KB DMAs: waves 0-1 cover B, waves 2-3 cover A.
// ---------------------------------------------------------------------------
__device__ __forceinline__ void prefetch_pair(const unsigned short* __restrict__ Bt,
                                              const unsigned short* __restrict__ At,
                                              unsigned short* stage,
                                              int wave, int lane) {
  const char* gb = (wave < 2) ? ((const char*)Bt + wave * 4096)
                              : ((const char*)At + (wave - 2) * 4096);
  char* lb = (char*)stage + wave * 4096;
#pragma unroll
  for (int i = 0; i < 4; ++i)
    async_cp16(gb + i * 1024 + lane * 16, lb + i * 1024);
}

__device__ __forceinline__ void mfma_step(const unsigned short* stage,
                                          float4v acc[4][4],
                                          int wm, int wn, int quad, int l16) {
  const unsigned short* Blds = stage;        // B tile at offset 0
  const unsigned short* Alds = stage + TS;   // A tile at +8192 B
  const int sw = (l16 & 7) << 3;             // row&7 == l16&7 (wm,i*16 mult of 16)
  short8v a[4], b[4];
#pragma unroll
  for (int i = 0; i < 4; ++i) {
    int r = wm + i * 16 + l16;
    a[i] = *(const short8v*)(Alds + (((r << 5) + (quad << 3)) ^ sw));
  }
#pragma unroll
  for (int j = 0; j < 4; ++j) {
    int r = wn + j * 16 + l16;
    b[j] = *(const short8v*)(Blds + (((r << 5) + (quad << 3)) ^ sw));
  }
#pragma unroll
  for (int i = 0; i < 4; ++i)
#pragma unroll
    for (int j = 0; j < 4; ++j)
      acc[i][j] = __builtin_amdgcn_mfma_f32_16x16x32_bf16(a[i], b[j], acc[i][j], 0, 0, 0);
}

// depth-2 pipeline, 4 loads/wave/batch: at iter kt (kt<=29) batches kt+1 and
// kt+2 are in flight (8 loads) -> vmcnt(8) retires batch kt. Tail 4/0.
#define WAIT_VM8()  asm volatile("s_waitcnt vmcnt(8)" ::: "memory")
#define WAIT_VM4()  asm volatile("s_waitcnt vmcnt(4)" ::: "memory")
#define WAIT_VM0()  asm volatile("s_waitcnt vmcnt(0)" ::: "memory")
#define RAW_BAR()   asm volatile("s_barrier" ::: "memory")

// ---------------------------------------------------------------------------
// pass 1: pre_zr = [x|h] @ B1 ; z = sigmoid -> Z ; r -> HRt = bf16(h*r)
// grid 2048 linear; swizzle: xcd=b&7, q=b>>3, nt=q&7, mt=(b&7)*32+(q>>3)
// ---------------------------------------------------------------------------
__global__ __launch_bounds__(256, 3) void gemm_zr(
    const float* __restrict__ h,
    const unsigned short* __restrict__ XHt,
    const unsigned short* __restrict__ Wt,
    const float* __restrict__ Wz_b, const float* __restrict__ Uz_b,
    const float* __restrict__ Wr_b, const float* __restrict__ Ur_b,
    unsigned short* __restrict__ Z, unsigned short* __restrict__ HRt) {
  __shared__ __align__(16) unsigned short Stg[NBUF][STAGE_SHORTS];  // 48 KB
  const int tid = threadIdx.x;
  const int wave = tid >> 6, lane = tid & 63;
  const int quad = lane >> 4, l16 = lane & 15;
  const int b = blockIdx.x;
  const int q = b >> 3;
  const int nt = q & 7;                   // 0..7
  const int mt = (b & 7) * 32 + (q >> 3); // 0..255
  const int m0 = mt * 128;
  const int wm = (wave >> 1) * 64, wn = (wave & 1) * 64;

  float4v acc[4][4] = {};

  const unsigned short* Abase = XHt + (size_t)(mt * 32) * TS;
  prefetch_pair(Wt + (size_t)(0 * 8 + nt) * TS, Abase + (size_t)0 * TS,
                Stg[0], wave, lane);
  prefetch_pair(Wt + (size_t)(1 * 8 + nt) * TS, Abase + (size_t)1 * TS,
                Stg[1], wave, lane);
  for (int kt = 0; kt < 32; ++kt) {
    if (kt <= 29) {
      prefetch_pair(Wt + (size_t)((kt + 2) * 8 + nt) * TS,
                    Abase + (size_t)(kt + 2) * TS,
                    Stg[(kt + 2) % NBUF], wave, lane);
      WAIT_VM8();
    } else if (kt == 30) {
      WAIT_VM4();
    } else {
      WAIT_VM0();
    }
    RAW_BAR();
    mfma_step(Stg[kt % NBUF], acc, wm, wn, quad, l16);
    RAW_BAR();
  }

  const int n0 = nt * 128;
  if (n0 < 512) {
    // z gate
#pragma unroll
    for (int j = 0; j < 4; ++j) {
      int n = n0 + wn + j * 16 + l16;
      float bias = Wz_b[n] + Uz_b[n];
#pragma unroll
      for (int i = 0; i < 4; ++i) {
#pragma unroll
        for (int reg = 0; reg < 4; ++reg) {
          int m = m0 + wm + i * 16 + quad * 4 + reg;
          float v = fast_sigmoid(acc[i][j][reg] + bias);
          Z[(size_t)m * HD + n] = f2bf(v);
        }
      }
    }
  } else {
    // r gate -> hr = h*r, stored pre-tiled (swizzled) as pass-2 A tiles
#pragma unroll
    for (int j = 0; j < 4; ++j) {
      int nn = (n0 - 512) + wn + j * 16 + l16;   // 0..511
      float bias = Wr_b[nn] + Ur_b[nn];
      int ktile = nn >> 5, kc = nn & 31;
#pragma unroll
      for (int i = 0; i < 4; ++i) {
#pragma unroll
        for (int reg = 0; reg < 4; ++reg) {
          int m = m0 + wm + i * 16 + quad * 4 + reg;
          float rv = fast_sigmoid(acc[i][j][reg] + bias);
          float hv = h[(size_t)m * HD + nn];
          int mr = m & 127;
          HRt[(size_t)(mt * 16 + ktile) * TS + swz_idx(mr, kc)] = f2bf(hv * rv);
        }
      }
    }
  }
}

// ---------------------------------------------------------------------------
// pass 2: pre_h = [x|hr] @ B2 ; ht = tanh ; h_next = h + z*(ht - h) -> out x2
// grid 1024 linear; swizzle: xcd=b&7, q=b>>3, nt=q&3, mt=(b&7)*32+(q>>2)
// ---------------------------------------------------------------------------
__global__ __launch_bounds__(256, 3) void gemm_out(
    const float* __restrict__ h,
    const unsigned short* __restrict__ XHt,
    const unsigned short* __restrict__ Wt,
    const float* __restrict__ Wh_b, const float* __restrict__ Uh_b,
    const unsigned short* __restrict__ Z, const unsigned short* __restrict__ HRt,
    float* __restrict__ out) {
  __shared__ __align__(16) unsigned short Stg[NBUF][STAGE_SHORTS];  // 48 KB
  const int tid = threadIdx.x;
  const int wave = tid >> 6, lane = tid & 63;
  const int quad = lane >> 4, l16 = lane & 15;
  const int b = blockIdx.x;
  const int q = b >> 3;
  const int nt = q & 3;                   // 0..3
  const int mt = (b & 7) * 32 + (q >> 2); // 0..255
  const int m0 = mt * 128;
  const int wm = (wave >> 1) * 64, wn = (wave & 1) * 64;

  float4v acc[4][4] = {};

  const unsigned short* Ax = XHt + (size_t)(mt * 32) * TS;  // kt 0..15 (x part)
  const unsigned short* Ah = HRt + (size_t)(mt * 16) * TS;  // kt 16..31 (hr part)
#define ATP(kn) ((kn) < 16 ? (Ax + (size_t)(kn) * TS) : (Ah + (size_t)((kn) - 16) * TS))
  prefetch_pair(Wt + (size_t)(0 * 4 + nt) * TS, ATP(0), Stg[0], wave, lane);
  prefetch_pair(Wt + (size_t)(1 * 4 + nt) * TS, ATP(1), Stg[1], wave, lane);
  for (int kt = 0; kt < 32; ++kt) {
    if (kt <= 29) {
      int kn = kt + 2;
      prefetch_pair(Wt + (size_t)(kn * 4 + nt) * TS, ATP(kn),
                    Stg[kn % NBUF], wave, lane);
      WAIT_VM8();
    } else if (kt == 30) {
      WAIT_VM4();
    } else {
      WAIT_VM0();
    }
    RAW_BAR();
    mfma_step(Stg[kt % NBUF], acc, wm, wn, quad, l16);
    RAW_BAR();
  }
#undef ATP

  const int n0 = nt * 128;
#pragma unroll
  for (int j = 0; j < 4; ++j) {
    int n = n0 + wn + j * 16 + l16;
    float bias = Wh_b[n] + Uh_b[n];
#pragma unroll
    for (int i = 0; i < 4; ++i) {
#pragma unroll
      for (int reg = 0; reg < 4; ++reg) {
        int m = m0 + wm + i * 16 + quad * 4 + reg;
        size_t idx = (size_t)m * HD + n;
        float ht = fast_tanh(acc[i][j][reg] + bias);
        float hv = h[idx];
        float zv = bf2f(Z[idx]);
        float o = fmaf(zv, ht - hv, hv);
        out[idx] = o;
        out[(size_t)BATCH * HD + idx] = o;
      }
    }
  }
}

// ---------------------------------------------------------------------------
extern "C" void kernel_launch(void* const* d_in, const int* in_sizes, int n_in,
                              void* d_out, int out_size, void* d_ws, size_t ws_size,
                              hipStream_t stream) {
  const float* x    = (const float*)d_in[0];
  const float* h    = (const float*)d_in[1];
  const float* Wz_w = (const float*)d_in[2];
  const float* Wz_b = (const float*)d_in[3];
  const float* Wr_w = (const float*)d_in[4];
  const float* Wr_b = (const float*)d_in[5];
  const float* Wh_w = (const float*)d_in[6];
  const float* Wh_b = (const float*)d_in[7];
  const float* Uz_w = (const float*)d_in[8];
  const float* Uz_b = (const float*)d_in[9];
  const float* Ur_w = (const float*)d_in[10];
  const float* Ur_b = (const float*)d_in[11];
  const float* Uh_w = (const float*)d_in[12];
  const float* Uh_b = (const float*)d_in[13];
  float* out = (float*)d_out;

  char* ws = (char*)d_ws;
  unsigned short* Wzr_t = (unsigned short*)(ws);                //  2,097,152 B
  unsigned short* Whh_t = (unsigned short*)(ws + 2097152);      //  1,048,576 B
  unsigned short* XHt   = (unsigned short*)(ws + 3145728);      // 67,108,864 B
  unsigned short* HRt   = (unsigned short*)(ws + 70254592);     // 33,554,432 B
  unsigned short* Z     = (unsigned short*)(ws + 103809024);    // 33,554,432 B

  prep_all<<<14336, 256, 0, stream>>>(x, h, Wz_w, Wr_w, Uz_w, Ur_w, Wh_w, Uh_w,
                                      XHt, Wzr_t, Whh_t);
  gemm_zr<<<2048, 256, 0, stream>>>(h, XHt, Wzr_t, Wz_b, Uz_b, Wr_b, Ur_b, Z, HRt);
  gemm_out<<<1024, 256, 0, stream>>>(h, XHt, Whh_t, Wh_b, Uh_b, Z, HRt, out);
}